// Round 9
// baseline (163.665 us; speedup 1.0000x reference)
//
#include <hip/hip_runtime.h>

typedef float f32x4 __attribute__((ext_vector_type(4)));
typedef short bf16x8 __attribute__((ext_vector_type(8)));

__device__ __forceinline__ unsigned short f2bf(float f) {
  unsigned u = __builtin_bit_cast(unsigned, f);
  u = (u + 0x7FFFu + ((u >> 16) & 1u)) >> 16;
  return (unsigned short)u;
}

// async global->LDS, 16B per lane. Dest param = wave-uniform base; HW adds lane*16B.
__device__ __forceinline__ void async16(const unsigned short* g, unsigned short* l) {
  __builtin_amdgcn_global_load_lds(
      (__attribute__((address_space(1))) void*)g,
      (__attribute__((address_space(3))) void*)l, 16, 0, 0);
}

// xt padded layout: [b][row 0..129][col 0..129][ch 0..127] bf16, borders zero.
#define XT_ROW 16640              // 130*128 elems per padded row

// ---------------------------------------------------------------------------
// Kernel 1: x (B,C,H,W) f32 -> xt padded bf16 [b][y+1][col+1][c], + row sums
// ---------------------------------------------------------------------------
__global__ __launch_bounds__(256) void k_transpose(const float* __restrict__ x,
                                                   unsigned short* __restrict__ xt,
                                                   float* __restrict__ rowsum) {
  __shared__ unsigned short tile[128][128];
  __shared__ float psum[128][8];
  const int y = blockIdx.x, b = blockIdx.y;
  const int t = threadIdx.x;
  const int colb = (t & 7) * 16;
  const int cp = t >> 3;
  const int swz = (t & 7) << 3;
  for (int ci = 0; ci < 4; ++ci) {
    const int c = ci * 32 + cp;
    const int c2 = c ^ swz;
    const float* src = x + (((size_t)(b * 128 + c) * 128 + y) * 128 + colb);
    float s = 0.f;
#pragma unroll
    for (int j = 0; j < 16; j += 4) {
      float4 v = *(const float4*)(src + j);
      s += v.x + v.y + v.z + v.w;
      tile[colb + j + 0][c2] = f2bf(v.x);
      tile[colb + j + 1][c2] = f2bf(v.y);
      tile[colb + j + 2][c2] = f2bf(v.z);
      tile[colb + j + 3][c2] = f2bf(v.w);
    }
    psum[c][t & 7] = s;
  }
  __syncthreads();
#pragma unroll
  for (int it = 0; it < 8; ++it) {
    const int slot = t + it * 256;
    const int col = slot >> 4;
    const int cg = (slot & 15) * 8;
    const int c2 = cg ^ (((col >> 4) & 7) << 3);
    uint4 vv = *(const uint4*)&tile[col][c2];
    *(uint4*)(xt + (((size_t)b * 130 + y + 1) * 130 + col + 1) * 128 + cg) = vv;
  }
  if (t < 128) {
    float r = 0.f;
#pragma unroll
    for (int j = 0; j < 8; ++j) r += psum[t][j];
    rowsum[((size_t)b * 128 + t) * 128 + y] = r;
  }
}

// ---------------------------------------------------------------------------
// Kernel 1b: zero the padded borders of xt
// ---------------------------------------------------------------------------
__global__ __launch_bounds__(256) void k_border(unsigned short* __restrict__ xt) {
  const int b = blockIdx.y;
  const int idx = blockIdx.x * 256 + threadIdx.x;
  if (idx >= 8256) return;
  int row, col, ck;
  if (idx < 4160) {
    row = (idx < 2080) ? 0 : 129;
    const int s = idx % 2080;
    col = s >> 4;
    ck = s & 15;
  } else {
    const int s = idx - 4160;
    row = (s >> 5) + 1;
    col = (s & 16) ? 129 : 0;
    ck = s & 15;
  }
  uint4 z = {0, 0, 0, 0};
  *(uint4*)(xt + ((size_t)b * 130 + row) * 130 * 128 + (size_t)col * 128 + ck * 8) = z;
}

// ---------------------------------------------------------------------------
// Kernel 2: rowsums -> pooled -> attention MLP -> softmax -> attn, agg_b
// ---------------------------------------------------------------------------
__global__ __launch_bounds__(128) void k_attn(const float* __restrict__ rowsum,
                                              const float* __restrict__ aw1,
                                              const float* __restrict__ ab1,
                                              const float* __restrict__ aw2,
                                              const float* __restrict__ ab2,
                                              const float* __restrict__ bias,
                                              float* __restrict__ attn,
                                              float* __restrict__ aggb) {
  __shared__ float pooled[128];
  __shared__ float h[32];
  __shared__ float at[4];
  const int b = blockIdx.x, t = threadIdx.x;
  const float* rs = rowsum + (size_t)(b * 128 + t) * 128;
  float s = 0.f;
  for (int yy = 0; yy < 128; ++yy) s += rs[yy];
  pooled[t] = s * (1.f / 16384.f);
  __syncthreads();
  if (t < 32) {
    float hv = ab1[t];
    for (int c = 0; c < 128; ++c) hv += pooled[c] * aw1[t * 128 + c];
    h[t] = fmaxf(hv, 0.f);
  }
  __syncthreads();
  if (t < 4) {
    float sc = ab2[t];
    for (int a = 0; a < 32; ++a) sc += h[a] * aw2[t * 32 + a];
    at[t] = sc * (1.f / 30.f);
  }
  __syncthreads();
  if (t == 0) {
    float m = fmaxf(fmaxf(at[0], at[1]), fmaxf(at[2], at[3]));
    float e0 = __expf(at[0] - m), e1 = __expf(at[1] - m);
    float e2 = __expf(at[2] - m), e3 = __expf(at[3] - m);
    float inv = 1.f / (e0 + e1 + e2 + e3);
    at[0] = e0 * inv; at[1] = e1 * inv; at[2] = e2 * inv; at[3] = e3 * inv;
  }
  __syncthreads();
  if (t < 4) attn[b * 4 + t] = at[t];
  float ab = 0.f;
  for (int k = 0; k < 4; ++k) ab += at[k] * bias[k * 128 + t];
  aggb[b * 128 + t] = ab;
}

// ---------------------------------------------------------------------------
// Kernel 3: aggregate weights over K, bf16. Slab per (b, step s):
//   aggw[((b*36 + s)*512 + k8*128 + o)*8 + e], step-channel = k8*8 + e.
//   -> A staging is identity-linear; A-frag ds_read = base + immediates.
// ---------------------------------------------------------------------------
__global__ __launch_bounds__(256) void k_aggw(const float* __restrict__ weight,
                                              const float* __restrict__ attn,
                                              unsigned short* __restrict__ aggw) {
  const int fid = blockIdx.x * 256 + threadIdx.x;
  const int e = fid & 7;
  const int o = (fid >> 3) & 127;
  const int k8 = (fid >> 10) & 3;
  const int rest = fid >> 12;      // b*36 + s
  const int s = rest % 36;
  const int b = rest / 36;
  const int c = ((s & 3) << 5) + k8 * 8 + e;
  const int pq = s >> 2;
  const size_t src = (size_t)o * 1152 + (size_t)c * 9 + pq;
  float v = attn[b * 4 + 0] * weight[src]
          + attn[b * 4 + 1] * weight[src + 147456]
          + attn[b * 4 + 2] * weight[src + 2 * 147456]
          + attn[b * 4 + 3] * weight[src + 3 * 147456];
  aggw[fid] = f2bf(v);
}

// ---------------------------------------------------------------------------
// Kernel 4: conv implicit GEMM, x-window resident in LDS, NO-SWIZZLE layouts:
//   B window [4 rows][16 k8][128 col][8ch] (128 KB, staged once)
//   A ring   4 x [4 k8][128 o][8ch]        (32 KB, streamed 2-ahead)
// Every ds_read = per-lane base VGPR + compile-time immediate; contiguous
// lanes -> conflict-free by construction. 8 waves (2M x 4N), 64x64/wave,
// barrier+vmcnt(0) per 2-step group, T5 setprio.
// ---------------------------------------------------------------------------
__global__ __launch_bounds__(512, 1) void k_conv(const unsigned short* __restrict__ xt,
                                                 const unsigned short* __restrict__ aggw,
                                                 const float* __restrict__ aggb,
                                                 float* __restrict__ out) {
  __shared__ unsigned short lds[81920];  // B win elems [0,65536); A ring @65536
  const int id = blockIdx.x;
  const int swz = (id & 7) * 128 + (id >> 3);   // 1024 % 8 == 0: bijective
  const int b = swz >> 6;
  const int y0 = (swz & 63) * 2;
  const int t = threadIdx.x;
  const int lane = t & 63, w = t >> 6;
  const int mw = w >> 2, nw = w & 3;
  const int l15 = lane & 15, lk = lane >> 4;

  // ---- prologue: stage B window [row][k8][col][8], 16 chunks/thread -------
  {
    const unsigned short* xb = xt + (size_t)(b * 130 + y0) * XT_ROW;
#pragma unroll
    for (int i = 0; i < 16; ++i) {
      const int idx = i * 512 + t;               // this thread's chunk
      const int row = idx >> 11, k8 = (idx >> 7) & 15, col = idx & 127;
      async16(xb + ((size_t)row * 130 + col + 1) * 128 + k8 * 8,
              &lds[0] + (size_t)(i * 512 + w * 64) * 8);
    }
  }
  // ---- A staging: 1 chunk/thread/tile, identity-linear --------------------
  const unsigned short* aS = aggw + (size_t)b * 147456 + t * 8;
  unsigned short* aldsw = &lds[65536] + w * 512;

#define STAGE_A(buf, s) async16(aS + (s) * 4096, aldsw + (buf) * 4096)

  STAGE_A(0, 0);
  STAGE_A(1, 1);

  const int r_ = nw >> 1;                   // y-row within pair
  const int px0 = (nw & 1) * 64 + l15;      // output col base
  const unsigned short* Bb = &lds[0] + r_ * 16384 + lk * 1024 + px0 * 8;
  const unsigned short* Ab = &lds[65536] + (lk * 128 + mw * 64 + l15) * 8;
  f32x4 acc[4][4] = {};

#pragma unroll
  for (int g = 0; g < 18; ++g) {
    asm volatile("s_waitcnt vmcnt(0)" ::: "memory");
    __builtin_amdgcn_sched_barrier(0);
    __builtin_amdgcn_s_barrier();
    __builtin_amdgcn_sched_barrier(0);
    if (g + 1 < 18) { STAGE_A((2 * g + 2) & 3, 2 * g + 2);
                      STAGE_A((2 * g + 3) & 3, 2 * g + 3); }
    __builtin_amdgcn_sched_barrier(0);
#pragma unroll
    for (int ss = 0; ss < 2; ++ss) {
      const int s = 2 * g + ss;
      const int tap = s >> 2, cc = s & 3;
      const int p = tap / 3, q = tap - 3 * p;
      bf16x8 af[4], bfr[4];
#pragma unroll
      for (int mi = 0; mi < 4; ++mi)
        af[mi] = *(const bf16x8*)(Ab + (s & 3) * 4096 + mi * 128);
#pragma unroll
      for (int ni = 0; ni < 4; ++ni) {
        if ((q == 0 && ni == 0) || (q == 2 && ni == 3)) {
          const int icol = px0 + ni * 16 + q - 1;
          const int ccl = icol < 0 ? 0 : (icol > 127 ? 127 : icol);
          bfr[ni] = *(const bf16x8*)(&lds[0] + (r_ + p) * 16384
                                     + (cc * 4 + lk) * 1024 + ccl * 8);
          if (icol < 0 || icol > 127) bfr[ni] = (bf16x8)0;
        } else {
          bfr[ni] = *(const bf16x8*)(Bb + p * 16384 + cc * 4096
                                     + (ni * 16 + q - 1) * 8);
        }
      }
      __builtin_amdgcn_s_setprio(1);
#pragma unroll
      for (int mi = 0; mi < 4; ++mi)
#pragma unroll
        for (int ni = 0; ni < 4; ++ni)
          acc[mi][ni] = __builtin_amdgcn_mfma_f32_16x16x32_bf16(af[mi], bfr[ni], acc[mi][ni], 0, 0, 0);
      __builtin_amdgcn_s_setprio(0);
    }
  }
#undef STAGE_A

  // epilogue
  const int y = y0 + r_;
  const int colb = (nw & 1) * 64 + l15;
#pragma unroll
  for (int mi = 0; mi < 4; ++mi) {
    const int o = mw * 64 + mi * 16 + lk * 4;
#pragma unroll
    for (int rr = 0; rr < 4; ++rr) {
      const float bsv = aggb[b * 128 + o + rr];
      float* orow = out + ((size_t)(b * 128 + o + rr) * 128 + y) * 128 + colb;
      orow[0]  = acc[mi][0][rr] + bsv;
      orow[16] = acc[mi][1][rr] + bsv;
      orow[32] = acc[mi][2][rr] + bsv;
      orow[48] = acc[mi][3][rr] + bsv;
    }
  }
}

// ---------------------------------------------------------------------------
extern "C" void kernel_launch(void* const* d_in, const int* in_sizes, int n_in,
                              void* d_out, int out_size, void* d_ws, size_t ws_size,
                              hipStream_t stream) {
  const float* x      = (const float*)d_in[0];
  const float* weight = (const float*)d_in[1];
  const float* bias   = (const float*)d_in[2];
  const float* aw1    = (const float*)d_in[3];
  const float* ab1    = (const float*)d_in[4];
  const float* aw2    = (const float*)d_in[5];
  const float* ab2    = (const float*)d_in[6];
  float* out = (float*)d_out;

  char* ws = (char*)d_ws;
  unsigned short* xt   = (unsigned short*)ws;                        // 69,222,400 B
  unsigned short* aggw = (unsigned short*)(ws + 69222400);           //  4,718,592 B
  float* rowsum        = (float*)(ws + 69222400 + 4718592);          //  1,048,576 B
  float* attn          = (float*)(ws + 69222400 + 4718592 + 1048576);         // 256 B
  float* aggb          = (float*)(ws + 69222400 + 4718592 + 1048576 + 256);   // 8 KB

  hipLaunchKernelGGL(k_border, dim3(33, 16), dim3(256), 0, stream, xt);
  hipLaunchKernelGGL(k_transpose, dim3(128, 16), dim3(256), 0, stream, x, xt, rowsum);
  hipLaunchKernelGGL(k_attn, dim3(16), dim3(128), 0, stream,
                     rowsum, aw1, ab1, aw2, ab2, bias, attn, aggb);
  hipLaunchKernelGGL(k_aggw, dim3(9216), dim3(256), 0, stream, weight, attn, aggw);
  hipLaunchKernelGGL(k_conv, dim3(1024), dim3(512), 0, stream, xt, aggw, aggb, out);
}

// Round 10
// 157.812 us; speedup vs baseline: 1.0371x; 1.0371x over previous
//
#include <hip/hip_runtime.h>

typedef float f32x4 __attribute__((ext_vector_type(4)));
typedef short bf16x8 __attribute__((ext_vector_type(8)));

__device__ __forceinline__ unsigned short f2bf(float f) {
  unsigned u = __builtin_bit_cast(unsigned, f);
  u = (u + 0x7FFFu + ((u >> 16) & 1u)) >> 16;
  return (unsigned short)u;
}

// async global->LDS, 16B per lane. Dest param = wave-uniform base; HW adds lane*16B.
__device__ __forceinline__ void async16(const unsigned short* g, unsigned short* l) {
  __builtin_amdgcn_global_load_lds(
      (__attribute__((address_space(1))) void*)g,
      (__attribute__((address_space(3))) void*)l, 16, 0, 0);
}

// xt padded layout: [b][row 0..129][col 0..129][ch 0..127] bf16, borders zero.
#define XT_ROW 16640              // 130*128 elems per padded row

// ---------------------------------------------------------------------------
// Kernel 1: x (B,C,H,W) f32 -> xt padded bf16 [b][y+1][col+1][c], + row sums
// ---------------------------------------------------------------------------
__global__ __launch_bounds__(256) void k_transpose(const float* __restrict__ x,
                                                   unsigned short* __restrict__ xt,
                                                   float* __restrict__ rowsum) {
  __shared__ unsigned short tile[128][128];
  __shared__ float psum[128][8];
  const int y = blockIdx.x, b = blockIdx.y;
  const int t = threadIdx.x;
  const int colb = (t & 7) * 16;
  const int cp = t >> 3;
  const int swz = (t & 7) << 3;
  for (int ci = 0; ci < 4; ++ci) {
    const int c = ci * 32 + cp;
    const int c2 = c ^ swz;
    const float* src = x + (((size_t)(b * 128 + c) * 128 + y) * 128 + colb);
    float s = 0.f;
#pragma unroll
    for (int j = 0; j < 16; j += 4) {
      float4 v = *(const float4*)(src + j);
      s += v.x + v.y + v.z + v.w;
      tile[colb + j + 0][c2] = f2bf(v.x);
      tile[colb + j + 1][c2] = f2bf(v.y);
      tile[colb + j + 2][c2] = f2bf(v.z);
      tile[colb + j + 3][c2] = f2bf(v.w);
    }
    psum[c][t & 7] = s;
  }
  __syncthreads();
#pragma unroll
  for (int it = 0; it < 8; ++it) {
    const int slot = t + it * 256;
    const int col = slot >> 4;
    const int cg = (slot & 15) * 8;
    const int c2 = cg ^ (((col >> 4) & 7) << 3);
    uint4 vv = *(const uint4*)&tile[col][c2];
    *(uint4*)(xt + (((size_t)b * 130 + y + 1) * 130 + col + 1) * 128 + cg) = vv;
  }
  if (t < 128) {
    float r = 0.f;
#pragma unroll
    for (int j = 0; j < 8; ++j) r += psum[t][j];
    rowsum[((size_t)b * 128 + t) * 128 + y] = r;
  }
}

// ---------------------------------------------------------------------------
// Kernel 1b: zero the padded borders of xt
// ---------------------------------------------------------------------------
__global__ __launch_bounds__(256) void k_border(unsigned short* __restrict__ xt) {
  const int b = blockIdx.y;
  const int idx = blockIdx.x * 256 + threadIdx.x;
  if (idx >= 8256) return;
  int row, col, ck;
  if (idx < 4160) {
    row = (idx < 2080) ? 0 : 129;
    const int s = idx % 2080;
    col = s >> 4;
    ck = s & 15;
  } else {
    const int s = idx - 4160;
    row = (s >> 5) + 1;
    col = (s & 16) ? 129 : 0;
    ck = s & 15;
  }
  uint4 z = {0, 0, 0, 0};
  *(uint4*)(xt + ((size_t)b * 130 + row) * 130 * 128 + (size_t)col * 128 + ck * 8) = z;
}

// ---------------------------------------------------------------------------
// Kernel 2: rowsums -> pooled -> attention MLP -> softmax -> attn, agg_b
// ---------------------------------------------------------------------------
__global__ __launch_bounds__(128) void k_attn(const float* __restrict__ rowsum,
                                              const float* __restrict__ aw1,
                                              const float* __restrict__ ab1,
                                              const float* __restrict__ aw2,
                                              const float* __restrict__ ab2,
                                              const float* __restrict__ bias,
                                              float* __restrict__ attn,
                                              float* __restrict__ aggb) {
  __shared__ float pooled[128];
  __shared__ float h[32];
  __shared__ float at[4];
  const int b = blockIdx.x, t = threadIdx.x;
  const float* rs = rowsum + (size_t)(b * 128 + t) * 128;
  float s = 0.f;
  for (int yy = 0; yy < 128; ++yy) s += rs[yy];
  pooled[t] = s * (1.f / 16384.f);
  __syncthreads();
  if (t < 32) {
    float hv = ab1[t];
    for (int c = 0; c < 128; ++c) hv += pooled[c] * aw1[t * 128 + c];
    h[t] = fmaxf(hv, 0.f);
  }
  __syncthreads();
  if (t < 4) {
    float sc = ab2[t];
    for (int a = 0; a < 32; ++a) sc += h[a] * aw2[t * 32 + a];
    at[t] = sc * (1.f / 30.f);
  }
  __syncthreads();
  if (t == 0) {
    float m = fmaxf(fmaxf(at[0], at[1]), fmaxf(at[2], at[3]));
    float e0 = __expf(at[0] - m), e1 = __expf(at[1] - m);
    float e2 = __expf(at[2] - m), e3 = __expf(at[3] - m);
    float inv = 1.f / (e0 + e1 + e2 + e3);
    at[0] = e0 * inv; at[1] = e1 * inv; at[2] = e2 * inv; at[3] = e3 * inv;
  }
  __syncthreads();
  if (t < 4) attn[b * 4 + t] = at[t];
  float ab = 0.f;
  for (int k = 0; k < 4; ++k) ab += at[k] * bias[k * 128 + t];
  aggb[b * 128 + t] = ab;
}

// ---------------------------------------------------------------------------
// Kernel 3: aggregate weights over K, bf16, slab layout for BK=64:
//   aggw[((b*18 + s)*128 + o)*64 + kk], tap = s>>1, c = (s&1)*64 + kk
// ---------------------------------------------------------------------------
__global__ __launch_bounds__(256) void k_aggw(const float* __restrict__ weight,
                                              const float* __restrict__ attn,
                                              unsigned short* __restrict__ aggw) {
  const int fid = blockIdx.x * 256 + threadIdx.x;
  const int kk = fid & 63;
  const int o = (fid >> 6) & 127;
  const int rest = fid >> 13;      // b*18 + s
  const int s = rest % 18;
  const int b = rest / 18;
  const int c = ((s & 1) << 6) + kk;
  const int pq = s >> 1;
  const size_t src = (size_t)o * 1152 + (size_t)c * 9 + pq;
  float v = attn[b * 4 + 0] * weight[src]
          + attn[b * 4 + 1] * weight[src + 147456]
          + attn[b * 4 + 2] * weight[src + 2 * 147456]
          + attn[b * 4 + 3] * weight[src + 3 * 147456];
  aggw[fid] = f2bf(v);
}

// ---------------------------------------------------------------------------
// Kernel 4: conv implicit GEMM, 8-phase-style schedule (T3+T4 gate).
// BM=128(Cout) x BN=256(y-pair x 128 col), BK=64 (one tap/K-tile), 18 tiles.
// 512 thr / 8 waves (2M x 4N), 64x64/wave, acc 4x4.
// Tri-buffer LDS 144KB: per buf A[128][64] @0, B[256][64] @8192 elems.
// 2-tile-ahead staging, vmcnt(6) ONLY at tile boundary (T4); 4 phases/tile:
// {ds_read subtile + 2 stage-issues -> barrier -> setprio 8xMFMA -> barrier}.
// XOR both-sides swizzle folded into per-lane constant bases (zero VALU/step).
// ---------------------------------------------------------------------------
__global__ __launch_bounds__(512, 1) void k_conv(const unsigned short* __restrict__ xt,
                                                 const unsigned short* __restrict__ aggw,
                                                 const float* __restrict__ aggb,
                                                 float* __restrict__ out) {
  __shared__ unsigned short lds[73728];   // 3 bufs x 24576 elems
  const int id = blockIdx.x;
  const int swz = (id & 7) * 128 + (id >> 3);   // 1024 % 8 == 0: bijective
  const int b = swz >> 6;
  const int Y = (swz & 63) * 2;           // output y-pair base (= padded base row)
  const int t = threadIdx.x;
  const int lane = t & 63, w = t >> 6;
  const int mw = w >> 2, nw = w & 3;
  const int l15 = lane & 15, lk = lane >> 4;
  const int e7 = l15 & 7;
  const int sl0 = (lk ^ e7) * 8;          // slot for kk=0 (elems)
  const int sl1 = ((4 ^ lk) ^ e7) * 8;    // slot for kk=1
  const int baseA0 = (mw * 64 + l15) * 64 + sl0;
  const int baseA1 = (mw * 64 + l15) * 64 + sl1;
  const int baseB0 = 8192 + (nw * 64 + l15) * 64 + sl0;
  const int baseB1 = 8192 + (nw * 64 + l15) * 64 + sl1;

  // ---- staging sources (source-side XOR; LDS dest stays linear) ----------
  const unsigned short* aS[2];
#pragma unroll
  for (int i = 0; i < 2; ++i) {
    const int c = i * 512 + t, o = c >> 3, k8 = c & 7;
    aS[i] = aggw + (size_t)b * 147456 + o * 64 + ((k8 ^ (o & 7)) * 8);
  }
  const unsigned short* bS[4];
#pragma unroll
  for (int i = 0; i < 4; ++i) {
    const int c = i * 512 + t, n = c >> 3, k8 = c & 7;
    const int r = n >> 7, col = n & 127;
    bS[i] = xt + ((size_t)(b * 130 + Y + r) * 130 + col) * 128 + ((k8 ^ (n & 7)) * 8);
  }

#define STA(jw, s2, i) async16(aS[i] + (s2) * 8192,                            \
                               &lds[(jw) * 24576 + ((i) * 512 + w * 64) * 8])
#define STB(jw, i, p2, q2, c02) async16(bS[i] + (p2) * XT_ROW + (q2) * 128 + (c02), \
                               &lds[(jw) * 24576 + 8192 + ((i) * 512 + w * 64) * 8])

  // prologue: stage tiles 0 (tap0,c0=0) and 1 (tap0,c0=64)
  STA(0, 0, 0); STA(0, 0, 1);
  STB(0, 0, 0, 0, 0); STB(0, 1, 0, 0, 0); STB(0, 2, 0, 0, 0); STB(0, 3, 0, 0, 0);
  STA(1, 1, 0); STA(1, 1, 1);
  STB(1, 0, 0, 0, 64); STB(1, 1, 0, 0, 64); STB(1, 2, 0, 0, 64); STB(1, 3, 0, 0, 64);

  f32x4 acc[4][4] = {};

#pragma unroll
  for (int s = 0; s < 18; ++s) {
    const int jb = (s % 3) * 24576;
    const int s2 = s + 2, jw = s2 % 3;
    const int tap2 = s2 >> 1;
    const int p2 = tap2 / 3, q2 = tap2 - 3 * p2, c02 = (s2 & 1) << 6;
    const bool st = (s2 < 18);

    if (s < 17) { asm volatile("s_waitcnt vmcnt(6)" ::: "memory"); }
    else        { asm volatile("s_waitcnt vmcnt(0)" ::: "memory"); }
    __builtin_amdgcn_sched_barrier(0);
    __builtin_amdgcn_s_barrier();
    __builtin_amdgcn_sched_barrier(0);

    bf16x8 a0, a1, a2, a3, b0, b1, b2, b3;
    // ---- phase 0: kk=0, B all + A mi0,1 ; stage 2 A-loads of tile s+2 ----
    b0 = *(const bf16x8*)(&lds[jb + baseB0 + 0 * 1024]);
    b1 = *(const bf16x8*)(&lds[jb + baseB0 + 1 * 1024]);
    b2 = *(const bf16x8*)(&lds[jb + baseB0 + 2 * 1024]);
    b3 = *(const bf16x8*)(&lds[jb + baseB0 + 3 * 1024]);
    a0 = *(const bf16x8*)(&lds[jb + baseA0 + 0 * 1024]);
    a1 = *(const bf16x8*)(&lds[jb + baseA0 + 1 * 1024]);
    if (st) { STA(jw, s2, 0); STA(jw, s2, 1); }
    __builtin_amdgcn_s_barrier();
    __builtin_amdgcn_s_setprio(1);
    acc[0][0] = __builtin_amdgcn_mfma_f32_16x16x32_bf16(a0, b0, acc[0][0], 0, 0, 0);
    acc[0][1] = __builtin_amdgcn_mfma_f32_16x16x32_bf16(a0, b1, acc[0][1], 0, 0, 0);
    acc[0][2] = __builtin_amdgcn_mfma_f32_16x16x32_bf16(a0, b2, acc[0][2], 0, 0, 0);
    acc[0][3] = __builtin_amdgcn_mfma_f32_16x16x32_bf16(a0, b3, acc[0][3], 0, 0, 0);
    acc[1][0] = __builtin_amdgcn_mfma_f32_16x16x32_bf16(a1, b0, acc[1][0], 0, 0, 0);
    acc[1][1] = __builtin_amdgcn_mfma_f32_16x16x32_bf16(a1, b1, acc[1][1], 0, 0, 0);
    acc[1][2] = __builtin_amdgcn_mfma_f32_16x16x32_bf16(a1, b2, acc[1][2], 0, 0, 0);
    acc[1][3] = __builtin_amdgcn_mfma_f32_16x16x32_bf16(a1, b3, acc[1][3], 0, 0, 0);
    __builtin_amdgcn_s_setprio(0);
    __builtin_amdgcn_s_barrier();
    // ---- phase 1: kk=0, A mi2,3 ; stage 2 B-loads ----
    a2 = *(const bf16x8*)(&lds[jb + baseA0 + 2 * 1024]);
    a3 = *(const bf16x8*)(&lds[jb + baseA0 + 3 * 1024]);
    if (st) { STB(jw, 0, p2, q2, c02); STB(jw, 1, p2, q2, c02); }
    __builtin_amdgcn_s_barrier();
    __builtin_amdgcn_s_setprio(1);
    acc[2][0] = __builtin_amdgcn_mfma_f32_16x16x32_bf16(a2, b0, acc[2][0], 0, 0, 0);
    acc[2][1] = __builtin_amdgcn_mfma_f32_16x16x32_bf16(a2, b1, acc[2][1], 0, 0, 0);
    acc[2][2] = __builtin_amdgcn_mfma_f32_16x16x32_bf16(a2, b2, acc[2][2], 0, 0, 0);
    acc[2][3] = __builtin_amdgcn_mfma_f32_16x16x32_bf16(a2, b3, acc[2][3], 0, 0, 0);
    acc[3][0] = __builtin_amdgcn_mfma_f32_16x16x32_bf16(a3, b0, acc[3][0], 0, 0, 0);
    acc[3][1] = __builtin_amdgcn_mfma_f32_16x16x32_bf16(a3, b1, acc[3][1], 0, 0, 0);
    acc[3][2] = __builtin_amdgcn_mfma_f32_16x16x32_bf16(a3, b2, acc[3][2], 0, 0, 0);
    acc[3][3] = __builtin_amdgcn_mfma_f32_16x16x32_bf16(a3, b3, acc[3][3], 0, 0, 0);
    __builtin_amdgcn_s_setprio(0);
    __builtin_amdgcn_s_barrier();
    // ---- phase 2: kk=1, B all + A mi0,1 ; stage 2 B-loads ----
    b0 = *(const bf16x8*)(&lds[jb + baseB1 + 0 * 1024]);
    b1 = *(const bf16x8*)(&lds[jb + baseB1 + 1 * 1024]);
    b2 = *(const bf16x8*)(&lds[jb + baseB1 + 2 * 1024]);
    b3 = *(const bf16x8*)(&lds[jb + baseB1 + 3 * 1024]);
    a0 = *(const bf16x8*)(&lds[jb + baseA1 + 0 * 1024]);
    a1 = *(const bf16x8*)(&lds[jb + baseA1 + 1 * 1024]);
    if (st) { STB(jw, 2, p2, q2, c02); STB(jw, 3, p2, q2, c02); }
    __builtin_amdgcn_s_barrier();
    __builtin_amdgcn_s_setprio(1);
    acc[0][0] = __builtin_amdgcn_mfma_f32_16x16x32_bf16(a0, b0, acc[0][0], 0, 0, 0);
    acc[0][1] = __builtin_amdgcn_mfma_f32_16x16x32_bf16(a0, b1, acc[0][1], 0, 0, 0);
    acc[0][2] = __builtin_amdgcn_mfma_f32_16x16x32_bf16(a0, b2, acc[0][2], 0, 0, 0);
    acc[0][3] = __builtin_amdgcn_mfma_f32_16x16x32_bf16(a0, b3, acc[0][3], 0, 0, 0);
    acc[1][0] = __builtin_amdgcn_mfma_f32_16x16x32_bf16(a1, b0, acc[1][0], 0, 0, 0);
    acc[1][1] = __builtin_amdgcn_mfma_f32_16x16x32_bf16(a1, b1, acc[1][1], 0, 0, 0);
    acc[1][2] = __builtin_amdgcn_mfma_f32_16x16x32_bf16(a1, b2, acc[1][2], 0, 0, 0);
    acc[1][3] = __builtin_amdgcn_mfma_f32_16x16x32_bf16(a1, b3, acc[1][3], 0, 0, 0);
    __builtin_amdgcn_s_setprio(0);
    __builtin_amdgcn_s_barrier();
    // ---- phase 3: kk=1, A mi2,3 ----
    a2 = *(const bf16x8*)(&lds[jb + baseA1 + 2 * 1024]);
    a3 = *(const bf16x8*)(&lds[jb + baseA1 + 3 * 1024]);
    __builtin_amdgcn_s_barrier();
    __builtin_amdgcn_s_setprio(1);
    acc[2][0] = __builtin_amdgcn_mfma_f32_16x16x32_bf16(a2, b0, acc[2][0], 0, 0, 0);
    acc[2][1] = __builtin_amdgcn_mfma_f32_16x16x32_bf16(a2, b1, acc[2][1], 0, 0, 0);
    acc[2][2] = __builtin_amdgcn_mfma_f32_16x16x32_bf16(a2, b2, acc[2][2], 0, 0, 0);
    acc[2][3] = __builtin_amdgcn_mfma_f32_16x16x32_bf16(a2, b3, acc[2][3], 0, 0, 0);
    acc[3][0] = __builtin_amdgcn_mfma_f32_16x16x32_bf16(a3, b0, acc[3][0], 0, 0, 0);
    acc[3][1] = __builtin_amdgcn_mfma_f32_16x16x32_bf16(a3, b1, acc[3][1], 0, 0, 0);
    acc[3][2] = __builtin_amdgcn_mfma_f32_16x16x32_bf16(a3, b2, acc[3][2], 0, 0, 0);
    acc[3][3] = __builtin_amdgcn_mfma_f32_16x16x32_bf16(a3, b3, acc[3][3], 0, 0, 0);
    __builtin_amdgcn_s_setprio(0);
    // (boundary barrier of next tile closes this phase)
  }
#undef STA
#undef STB

  // epilogue: wave (mw,nw): y = Y + (nw>>1), colb = (nw&1)*64 + l15
  const int y = Y + (nw >> 1);
  const int colb = (nw & 1) * 64 + l15;
#pragma unroll
  for (int mi = 0; mi < 4; ++mi) {
    const int o = mw * 64 + mi * 16 + lk * 4;
#pragma unroll
    for (int rr = 0; rr < 4; ++rr) {
      const float bsv = aggb[b * 128 + o + rr];
      float* orow = out + ((size_t)(b * 128 + o + rr) * 128 + y) * 128 + colb;
      orow[0]  = acc[mi][0][rr] + bsv;
      orow[16] = acc[mi][1][rr] + bsv;
      orow[32] = acc[mi][2][rr] + bsv;
      orow[48] = acc[mi][3][rr] + bsv;
    }
  }
}

// ---------------------------------------------------------------------------
extern "C" void kernel_launch(void* const* d_in, const int* in_sizes, int n_in,
                              void* d_out, int out_size, void* d_ws, size_t ws_size,
                              hipStream_t stream) {
  const float* x      = (const float*)d_in[0];
  const float* weight = (const float*)d_in[1];
  const float* bias   = (const float*)d_in[2];
  const float* aw1    = (const float*)d_in[3];
  const float* ab1    = (const float*)d_in[4];
  const float* aw2    = (const float*)d_in[5];
  const float* ab2    = (const float*)d_in[6];
  float* out = (float*)d_out;

  char* ws = (char*)d_ws;
  unsigned short* xt   = (unsigned short*)ws;                        // 69,222,400 B
  unsigned short* aggw = (unsigned short*)(ws + 69222400);           //  4,718,592 B
  float* rowsum        = (float*)(ws + 69222400 + 4718592);          //  1,048,576 B
  float* attn          = (float*)(ws + 69222400 + 4718592 + 1048576);         // 256 B
  float* aggb          = (float*)(ws + 69222400 + 4718592 + 1048576 + 256);   // 8 KB

  hipLaunchKernelGGL(k_border, dim3(33, 16), dim3(256), 0, stream, xt);
  hipLaunchKernelGGL(k_transpose, dim3(128, 16), dim3(256), 0, stream, x, xt, rowsum);
  hipLaunchKernelGGL(k_attn, dim3(16), dim3(128), 0, stream,
                     rowsum, aw1, ab1, aw2, ab2, bias, attn, aggb);
  hipLaunchKernelGGL(k_aggw, dim3(9216), dim3(256), 0, stream, weight, attn, aggw);
  hipLaunchKernelGGL(k_conv, dim3(1024), dim3(512), 0, stream, xt, aggw, aggb, out);
}

// Round 12
// 155.036 us; speedup vs baseline: 1.0557x; 1.0179x over previous
//
#include <hip/hip_runtime.h>

typedef float f32x4 __attribute__((ext_vector_type(4)));
typedef short bf16x8 __attribute__((ext_vector_type(8)));

__device__ __forceinline__ unsigned short f2bf(float f) {
  unsigned u = __builtin_bit_cast(unsigned, f);
  u = (u + 0x7FFFu + ((u >> 16) & 1u)) >> 16;
  return (unsigned short)u;
}

// async global->LDS, 16B per lane. Dest param = wave-uniform base; HW adds lane*16B.
__device__ __forceinline__ void async16(const unsigned short* g, unsigned short* l) {
  __builtin_amdgcn_global_load_lds(
      (__attribute__((address_space(1))) void*)g,
      (__attribute__((address_space(3))) void*)l, 16, 0, 0);
}

// xt padded layout: [b][row 0..129][col 0..129][ch 0..127] bf16, borders zero.
#define XT_ROW 16640              // 130*128 elems per padded row

// ---------------------------------------------------------------------------
// Kernel 1: x (B,C,H,W) f32 -> xt padded bf16 [b][y+1][col+1][c], + row sums
// ---------------------------------------------------------------------------
__global__ __launch_bounds__(256) void k_transpose(const float* __restrict__ x,
                                                   unsigned short* __restrict__ xt,
                                                   float* __restrict__ rowsum) {
  __shared__ unsigned short tile[128][128];
  __shared__ float psum[128][8];
  const int y = blockIdx.x, b = blockIdx.y;
  const int t = threadIdx.x;
  const int colb = (t & 7) * 16;
  const int cp = t >> 3;
  const int swz = (t & 7) << 3;
  for (int ci = 0; ci < 4; ++ci) {
    const int c = ci * 32 + cp;
    const int c2 = c ^ swz;
    const float* src = x + (((size_t)(b * 128 + c) * 128 + y) * 128 + colb);
    float s = 0.f;
#pragma unroll
    for (int j = 0; j < 16; j += 4) {
      float4 v = *(const float4*)(src + j);
      s += v.x + v.y + v.z + v.w;
      tile[colb + j + 0][c2] = f2bf(v.x);
      tile[colb + j + 1][c2] = f2bf(v.y);
      tile[colb + j + 2][c2] = f2bf(v.z);
      tile[colb + j + 3][c2] = f2bf(v.w);
    }
    psum[c][t & 7] = s;
  }
  __syncthreads();
#pragma unroll
  for (int it = 0; it < 8; ++it) {
    const int slot = t + it * 256;
    const int col = slot >> 4;
    const int cg = (slot & 15) * 8;
    const int c2 = cg ^ (((col >> 4) & 7) << 3);
    uint4 vv = *(const uint4*)&tile[col][c2];
    *(uint4*)(xt + (((size_t)b * 130 + y + 1) * 130 + col + 1) * 128 + cg) = vv;
  }
  if (t < 128) {
    float r = 0.f;
#pragma unroll
    for (int j = 0; j < 8; ++j) r += psum[t][j];
    rowsum[((size_t)b * 128 + t) * 128 + y] = r;
  }
}

// ---------------------------------------------------------------------------
// Kernel 1b: zero the padded borders of xt
// ---------------------------------------------------------------------------
__global__ __launch_bounds__(256) void k_border(unsigned short* __restrict__ xt) {
  const int b = blockIdx.y;
  const int idx = blockIdx.x * 256 + threadIdx.x;
  if (idx >= 8256) return;
  int row, col, ck;
  if (idx < 4160) {
    row = (idx < 2080) ? 0 : 129;
    const int s = idx % 2080;
    col = s >> 4;
    ck = s & 15;
  } else {
    const int s = idx - 4160;
    row = (s >> 5) + 1;
    col = (s & 16) ? 129 : 0;
    ck = s & 15;
  }
  uint4 z = {0, 0, 0, 0};
  *(uint4*)(xt + ((size_t)b * 130 + row) * 130 * 128 + (size_t)col * 128 + ck * 8) = z;
}

// ---------------------------------------------------------------------------
// Kernel 2: rowsums -> pooled -> attention MLP -> softmax -> attn, agg_b
// ---------------------------------------------------------------------------
__global__ __launch_bounds__(128) void k_attn(const float* __restrict__ rowsum,
                                              const float* __restrict__ aw1,
                                              const float* __restrict__ ab1,
                                              const float* __restrict__ aw2,
                                              const float* __restrict__ ab2,
                                              const float* __restrict__ bias,
                                              float* __restrict__ attn,
                                              float* __restrict__ aggb) {
  __shared__ float pooled[128];
  __shared__ float h[32];
  __shared__ float at[4];
  const int b = blockIdx.x, t = threadIdx.x;
  const float* rs = rowsum + (size_t)(b * 128 + t) * 128;
  float s = 0.f;
  for (int yy = 0; yy < 128; ++yy) s += rs[yy];
  pooled[t] = s * (1.f / 16384.f);
  __syncthreads();
  if (t < 32) {
    float hv = ab1[t];
    for (int c = 0; c < 128; ++c) hv += pooled[c] * aw1[t * 128 + c];
    h[t] = fmaxf(hv, 0.f);
  }
  __syncthreads();
  if (t < 4) {
    float sc = ab2[t];
    for (int a = 0; a < 32; ++a) sc += h[a] * aw2[t * 32 + a];
    at[t] = sc * (1.f / 30.f);
  }
  __syncthreads();
  if (t == 0) {
    float m = fmaxf(fmaxf(at[0], at[1]), fmaxf(at[2], at[3]));
    float e0 = __expf(at[0] - m), e1 = __expf(at[1] - m);
    float e2 = __expf(at[2] - m), e3 = __expf(at[3] - m);
    float inv = 1.f / (e0 + e1 + e2 + e3);
    at[0] = e0 * inv; at[1] = e1 * inv; at[2] = e2 * inv; at[3] = e3 * inv;
  }
  __syncthreads();
  if (t < 4) attn[b * 4 + t] = at[t];
  float ab = 0.f;
  for (int k = 0; k < 4; ++k) ab += at[k] * bias[k * 128 + t];
  aggb[b * 128 + t] = ab;
}

// ---------------------------------------------------------------------------
// Kernel 3: aggregate weights over K, bf16, slab layout for BK=64:
//   aggw[((b*18 + s)*128 + o)*64 + kk], tap = s>>1, c = (s&1)*64 + kk
// ---------------------------------------------------------------------------
__global__ __launch_bounds__(256) void k_aggw(const float* __restrict__ weight,
                                              const float* __restrict__ attn,
                                              unsigned short* __restrict__ aggw) {
  const int fid = blockIdx.x * 256 + threadIdx.x;
  const int kk = fid & 63;
  const int o = (fid >> 6) & 127;
  const int rest = fid >> 13;      // b*18 + s
  const int s = rest % 18;
  const int b = rest / 18;
  const int c = ((s & 1) << 6) + kk;
  const int pq = s >> 1;
  const size_t src = (size_t)o * 1152 + (size_t)c * 9 + pq;
  float v = attn[b * 4 + 0] * weight[src]
          + attn[b * 4 + 1] * weight[src + 147456]
          + attn[b * 4 + 2] * weight[src + 2 * 147456]
          + attn[b * 4 + 3] * weight[src + 3 * 147456];
  aggw[fid] = f2bf(v);
}

// ---------------------------------------------------------------------------
// Kernel 4: conv implicit GEMM, per-wave 128x64 output tile (m201 geometry).
// BM=128(Cout) x BN=512 (4 y-rows x 128 cols), BK=64 (one tap/tile), 18 tiles.
// 512 thr / 8 N-waves, acc 8x4/wave. Double-buffer LDS 163840 B.
// 1-tile-ahead staging; vmcnt(0) at boundary (issued a full tile earlier).
// 4 phases/tile of 16 MFMA. r11 fix: B staging offset now includes the
// channel-half term ((s&1)<<6) that was dropped (absmax 4.0 bug).
// ---------------------------------------------------------------------------
__global__ __launch_bounds__(512, 2) void k_conv(const unsigned short* __restrict__ xt,
                                                 const unsigned short* __restrict__ aggw,
                                                 const float* __restrict__ aggb,
                                                 float* __restrict__ out) {
  __shared__ unsigned short lds[81920];  // 2 bufs x (A 8192 + B 32768) elems
  const int id = blockIdx.x;
  const int swz = (id & 7) * 64 + (id >> 3);   // 512 % 8 == 0: bijective
  const int b = swz >> 5;
  const int Y = (swz & 31) * 4;           // output y-quad base (= padded base row)
  const int t = threadIdx.x;
  const int lane = t & 63, nw = t >> 6;   // 8 N-waves
  const int l15 = lane & 15, lk = lane >> 4;
  const int e7 = l15 & 7;
  const int sl0 = (lk ^ e7) * 8;          // slot for kk=0 (elems)
  const int sl1 = ((4 ^ lk) ^ e7) * 8;    // slot for kk=1
  const int baseA0 = l15 * 64 + sl0;      // + mi*1024
  const int baseA1 = l15 * 64 + sl1;
  const int nrow = (nw >> 1) * 128 + (nw & 1) * 64 + l15;
  const int baseB0 = 8192 + nrow * 64 + sl0;   // + ni*1024
  const int baseB1 = 8192 + nrow * 64 + sl1;

  // ---- staging sources (source-side XOR; LDS dest linear) -----------------
  const unsigned short* aS[2];
#pragma unroll
  for (int i = 0; i < 2; ++i) {
    const int c = i * 512 + t, o = c >> 3, k8 = c & 7;
    aS[i] = aggw + (size_t)b * 147456 + o * 64 + ((k8 ^ (o & 7)) * 8);
  }
  const unsigned short* bS[8];
#pragma unroll
  for (int i = 0; i < 8; ++i) {
    const int c = i * 512 + t, n = c >> 3, k8 = c & 7;
    const int r = n >> 7, col = n & 127;
    bS[i] = xt + ((size_t)(b * 130 + Y + r) * 130 + col) * 128 + ((k8 ^ (col & 7)) * 8);
  }

  const int wu = (t >> 6) * 64;           // wave-uniform lane-block base
#define STA(jb, sv, i) async16(aS[i] + (size_t)(sv) * 8192,                    \
                               &lds[(jb) + ((i) * 512 + wu) * 8])
#define STB(jb, pqv, i) async16(bS[i] + (pqv),                                 \
                               &lds[(jb) + 8192 + ((i) * 512 + wu) * 8])

  // prologue: stage tile 0 (tap 0 => p=0,q=0,c0=0) into buf 0
  STA(0, 0, 0); STA(0, 0, 1);
#pragma unroll
  for (int i = 0; i < 8; ++i) STB(0, 0, i);

  f32x4 acc[8][4] = {};

#pragma unroll
  for (int s = 0; s < 18; ++s) {
    const int jb = (s & 1) * 40960;
    const int jn = ((s + 1) & 1) * 40960;
    const int s1 = s + 1;
    const int tap1 = s1 >> 1;
    const int p1 = tap1 / 3, q1 = tap1 - 3 * p1;
    const int pq1 = (p1 * 130 + q1) * 128 + ((s1 & 1) << 6);  // r11 FIX: + c0
    const bool st = (s1 < 18);

    // ---- tile boundary: all loads of tile s done (issued a full tile ago) --
    asm volatile("s_waitcnt vmcnt(0)" ::: "memory");
    __builtin_amdgcn_sched_barrier(0);
    __builtin_amdgcn_s_barrier();
    __builtin_amdgcn_sched_barrier(0);

    bf16x8 a0, a1, a2, a3, b0, b1, b2, b3;
    // ---- phase 0: kk=0, B0-3 + A0-3 ; stage 2A+2B of tile s+1 -------------
    b0 = *(const bf16x8*)(&lds[jb + baseB0 + 0 * 1024]);
    b1 = *(const bf16x8*)(&lds[jb + baseB0 + 1 * 1024]);
    b2 = *(const bf16x8*)(&lds[jb + baseB0 + 2 * 1024]);
    b3 = *(const bf16x8*)(&lds[jb + baseB0 + 3 * 1024]);
    a0 = *(const bf16x8*)(&lds[jb + baseA0 + 0 * 1024]);
    a1 = *(const bf16x8*)(&lds[jb + baseA0 + 1 * 1024]);
    a2 = *(const bf16x8*)(&lds[jb + baseA0 + 2 * 1024]);
    a3 = *(const bf16x8*)(&lds[jb + baseA0 + 3 * 1024]);
    if (st) { STA(jn, s1, 0); STA(jn, s1, 1); STB(jn, pq1, 0); STB(jn, pq1, 1); }
    __builtin_amdgcn_sched_barrier(0);
    __builtin_amdgcn_s_barrier();
    __builtin_amdgcn_sched_barrier(0);
    __builtin_amdgcn_s_setprio(1);
#pragma unroll
    for (int ni = 0; ni < 4; ++ni) {
      const bf16x8 bb = (ni == 0) ? b0 : (ni == 1) ? b1 : (ni == 2) ? b2 : b3;
      acc[0][ni] = __builtin_amdgcn_mfma_f32_16x16x32_bf16(a0, bb, acc[0][ni], 0, 0, 0);
      acc[1][ni] = __builtin_amdgcn_mfma_f32_16x16x32_bf16(a1, bb, acc[1][ni], 0, 0, 0);
      acc[2][ni] = __builtin_amdgcn_mfma_f32_16x16x32_bf16(a2, bb, acc[2][ni], 0, 0, 0);
      acc[3][ni] = __builtin_amdgcn_mfma_f32_16x16x32_bf16(a3, bb, acc[3][ni], 0, 0, 0);
    }
    __builtin_amdgcn_s_setprio(0);
    __builtin_amdgcn_s_barrier();
    // ---- phase 1: kk=0, A4-7 ; stage 2B ----------------------------------
    a0 = *(const bf16x8*)(&lds[jb + baseA0 + 4 * 1024]);
    a1 = *(const bf16x8*)(&lds[jb + baseA0 + 5 * 1024]);
    a2 = *(const bf16x8*)(&lds[jb + baseA0 + 6 * 1024]);
    a3 = *(const bf16x8*)(&lds[jb + baseA0 + 7 * 1024]);
    if (st) { STB(jn, pq1, 2); STB(jn, pq1, 3); }
    __builtin_amdgcn_sched_barrier(0);
    __builtin_amdgcn_s_barrier();
    __builtin_amdgcn_sched_barrier(0);
    __builtin_amdgcn_s_setprio(1);
#pragma unroll
    for (int ni = 0; ni < 4; ++ni) {
      const bf16x8 bb = (ni == 0) ? b0 : (ni == 1) ? b1 : (ni == 2) ? b2 : b3;
      acc[4][ni] = __builtin_amdgcn_mfma_f32_16x16x32_bf16(a0, bb, acc[4][ni], 0, 0, 0);
      acc[5][ni] = __builtin_amdgcn_mfma_f32_16x16x32_bf16(a1, bb, acc[5][ni], 0, 0, 0);
      acc[6][ni] = __builtin_amdgcn_mfma_f32_16x16x32_bf16(a2, bb, acc[6][ni], 0, 0, 0);
      acc[7][ni] = __builtin_amdgcn_mfma_f32_16x16x32_bf16(a3, bb, acc[7][ni], 0, 0, 0);
    }
    __builtin_amdgcn_s_setprio(0);
    __builtin_amdgcn_s_barrier();
    // ---- phase 2: kk=1, B0-3 + A0-3 ; stage 2B ---------------------------
    b0 = *(const bf16x8*)(&lds[jb + baseB1 + 0 * 1024]);
    b1 = *(const bf16x8*)(&lds[jb + baseB1 + 1 * 1024]);
    b2 = *(const bf16x8*)(&lds[jb + baseB1 + 2 * 1024]);
    b3 = *(const bf16x8*)(&lds[jb + baseB1 + 3 * 1024]);
    a0 = *(const bf16x8*)(&lds[jb + baseA1 + 0 * 1024]);
    a1 = *(const bf16x8*)(&lds[jb + baseA1 + 1 * 1024]);
    a2 = *(const bf16x8*)(&lds[jb + baseA1 + 2 * 1024]);
    a3 = *(const bf16x8*)(&lds[jb + baseA1 + 3 * 1024]);
    if (st) { STB(jn, pq1, 4); STB(jn, pq1, 5); }
    __builtin_amdgcn_sched_barrier(0);
    __builtin_amdgcn_s_barrier();
    __builtin_amdgcn_sched_barrier(0);
    __builtin_amdgcn_s_setprio(1);
#pragma unroll
    for (int ni = 0; ni < 4; ++ni) {
      const bf16x8 bb = (ni == 0) ? b0 : (ni == 1) ? b1 : (ni == 2) ? b2 : b3;
      acc[0][ni] = __builtin_amdgcn_mfma_f32_16x16x32_bf16(a0, bb, acc[0][ni], 0, 0, 0);
      acc[1][ni] = __builtin_amdgcn_mfma_f32_16x16x32_bf16(a1, bb, acc[1][ni], 0, 0, 0);
      acc[2][ni] = __builtin_amdgcn_mfma_f32_16x16x32_bf16(a2, bb, acc[2][ni], 0, 0, 0);
      acc[3][ni] = __builtin_amdgcn_mfma_f32_16x16x32_bf16(a3, bb, acc[3][ni], 0, 0, 0);
    }
    __builtin_amdgcn_s_setprio(0);
    __builtin_amdgcn_s_barrier();
    // ---- phase 3: kk=1, A4-7 ; stage 2B ----------------------------------
    a0 = *(const bf16x8*)(&lds[jb + baseA1 + 4 * 1024]);
    a1 = *(const bf16x8*)(&lds[jb + baseA1 + 5 * 1024]);
    a2 = *(const bf16x8*)(&lds[jb + baseA1 + 6 * 1024]);
    a3 = *(const bf16x8*)(&lds[jb + baseA1 + 7 * 1024]);
    if (st) { STB(jn, pq1, 6); STB(jn, pq1, 7); }
    __builtin_amdgcn_sched_barrier(0);
    __builtin_amdgcn_s_barrier();
    __builtin_amdgcn_sched_barrier(0);
    __builtin_amdgcn_s_setprio(1);
#pragma unroll
    for (int ni = 0; ni < 4; ++ni) {
      const bf16x8 bb = (ni == 0) ? b0 : (ni == 1) ? b1 : (ni == 2) ? b2 : b3;
      acc[4][ni] = __builtin_amdgcn_mfma_f32_16x16x32_bf16(a0, bb, acc[4][ni], 0, 0, 0);
      acc[5][ni] = __builtin_amdgcn_mfma_f32_16x16x32_bf16(a1, bb, acc[5][ni], 0, 0, 0);
      acc[6][ni] = __builtin_amdgcn_mfma_f32_16x16x32_bf16(a2, bb, acc[6][ni], 0, 0, 0);
      acc[7][ni] = __builtin_amdgcn_mfma_f32_16x16x32_bf16(a3, bb, acc[7][ni], 0, 0, 0);
    }
    __builtin_amdgcn_s_setprio(0);
    // (next tile's boundary barrier closes this phase)
  }
#undef STA
#undef STB

  // epilogue: wave nw: y = Y + (nw>>1), colb = (nw&1)*64 + l15
  const int y = Y + (nw >> 1);
  const int colb = (nw & 1) * 64 + l15;
#pragma unroll
  for (int mi = 0; mi < 8; ++mi) {
    const int o = mi * 16 + lk * 4;
#pragma unroll
    for (int rr = 0; rr < 4; ++rr) {
      const float bsv = aggb[b * 128 + o + rr];
      float* orow = out + ((size_t)(b * 128 + o + rr) * 128 + y) * 128 + colb;
      orow[0]  = acc[mi][0][rr] + bsv;
      orow[16] = acc[mi][1][rr] + bsv;
      orow[32] = acc[mi][2][rr] + bsv;
      orow[48] = acc[mi][3][rr] + bsv;
    }
  }
}

// ---------------------------------------------------------------------------
extern "C" void kernel_launch(void* const* d_in, const int* in_sizes, int n_in,
                              void* d_out, int out_size, void* d_ws, size_t ws_size,
                              hipStream_t stream) {
  const float* x      = (const float*)d_in[0];
  const float* weight = (const float*)d_in[1];
  const float* bias   = (const float*)d_in[2];
  const float* aw1    = (const float*)d_in[3];
  const float* ab1    = (const float*)d_in[4];
  const float* aw2    = (const float*)d_in[5];
  const float* ab2    = (const float*)d_in[6];
  float* out = (float*)d_out;

  char* ws = (char*)d_ws;
  unsigned short* xt   = (unsigned short*)ws;                        // 69,222,400 B
  unsigned short* aggw = (unsigned short*)(ws + 69222400);           //  4,718,592 B
  float* rowsum        = (float*)(ws + 69222400 + 4718592);          //  1,048,576 B
  float* attn          = (float*)(ws + 69222400 + 4718592 + 1048576);         // 256 B
  float* aggb          = (float*)(ws + 69222400 + 4718592 + 1048576 + 256);   // 8 KB

  hipLaunchKernelGGL(k_border, dim3(33, 16), dim3(256), 0, stream, xt);
  hipLaunchKernelGGL(k_transpose, dim3(128, 16), dim3(256), 0, stream, x, xt, rowsum);
  hipLaunchKernelGGL(k_attn, dim3(16), dim3(128), 0, stream,
                     rowsum, aw1, ab1, aw2, ab2, bias, attn, aggb);
  hipLaunchKernelGGL(k_aggw, dim3(9216), dim3(256), 0, stream, weight, attn, aggw);
  hipLaunchKernelGGL(k_conv, dim3(512), dim3(512), 0, stream, xt, aggw, aggb, out);
}